// Round 1
// baseline (1576.939 us; speedup 1.0000x reference)
//
#include <hip/hip_runtime.h>
#include <hip/hip_bf16.h>

#define T_TOK 16384
#define DM 1024
#define DF 4096
#define NE 8

typedef __attribute__((ext_vector_type(8))) short short8;
typedef __attribute__((ext_vector_type(4))) float f32x4;

__device__ __forceinline__ void gload_lds16(const void* g, void* l) {
  __builtin_amdgcn_global_load_lds((const __attribute__((address_space(1))) void*)g,
                                   (__attribute__((address_space(3))) void*)l, 16, 0, 0);
}

// ---------------- x -> bf16 ----------------
struct alignas(16) BF8 { __hip_bfloat16 v[8]; };

__global__ __launch_bounds__(256) void cvt_x_kernel(const float* __restrict__ x,
                                                    __hip_bfloat16* __restrict__ xb) {
  size_t i = (size_t)blockIdx.x * 256 + threadIdx.x;  // 0 .. T*DM/8-1
  const float4* s = (const float4*)x;
  float4 a = s[2 * i], b = s[2 * i + 1];
  BF8 o;
  o.v[0] = __float2bfloat16(a.x); o.v[1] = __float2bfloat16(a.y);
  o.v[2] = __float2bfloat16(a.z); o.v[3] = __float2bfloat16(a.w);
  o.v[4] = __float2bfloat16(b.x); o.v[5] = __float2bfloat16(b.y);
  o.v[6] = __float2bfloat16(b.z); o.v[7] = __float2bfloat16(b.w);
  ((BF8*)xb)[i] = o;
}

// ---------------- transpose + convert: src f32 [B][R][C] -> dst bf16 [B][C][R] ----------------
__global__ __launch_bounds__(256) void tcvt_kernel(const float* __restrict__ src,
                                                   __hip_bfloat16* __restrict__ dst,
                                                   int R, int C) {
  __shared__ float t[32][33];
  int b = blockIdx.z;
  int r0 = blockIdx.y * 32, c0 = blockIdx.x * 32;
  int tx = threadIdx.x & 31, ty = threadIdx.x >> 5;  // 32 x 8
  const float* s = src + ((size_t)b * R + r0) * C + c0;
#pragma unroll
  for (int yy = 0; yy < 32; yy += 8) t[ty + yy][tx] = s[(size_t)(ty + yy) * C + tx];
  __syncthreads();
  __hip_bfloat16* d = dst + ((size_t)b * C + c0) * R + r0;
#pragma unroll
  for (int yy = 0; yy < 32; yy += 8)
    d[(size_t)(ty + yy) * R + tx] = __float2bfloat16(t[tx][ty + yy]);
}

// ---------------- router: logits, softmax, top-2, counts ----------------
__global__ __launch_bounds__(256) void router_kernel(const float* __restrict__ x,
                                                     const float* __restrict__ wr,
                                                     int* __restrict__ counts,
                                                     int* __restrict__ topk_i,
                                                     float* __restrict__ topk_w) {
  __shared__ float4 wl[8 * 257];  // padded row stride to break bank aliasing
  int tid = threadIdx.x;
  for (int i = tid; i < 2048; i += 256) {
    int e = i >> 8, c = i & 255;
    wl[e * 257 + c] = ((const float4*)wr)[i];
  }
  __syncthreads();
  int tok = blockIdx.x * 32 + (tid >> 3);
  int e = tid & 7;
  const float4* xr = (const float4*)(x + (size_t)tok * DM);
  float s = 0.f;
  for (int c = 0; c < 256; c++) {
    float4 a = xr[c];
    float4 b = wl[e * 257 + c];
    s += a.x * b.x + a.y * b.y + a.z * b.z + a.w * b.w;
  }
  int lane = tid & 63;
  int base = lane & ~7;
  float l[8];
#pragma unroll
  for (int j = 0; j < 8; j++) l[j] = __shfl(s, base + j, 64);
  // softmax (all 8 lanes of the group compute identically)
  float mx = l[0];
#pragma unroll
  for (int j = 1; j < 8; j++) mx = fmaxf(mx, l[j]);
  float p[8], sum = 0.f;
#pragma unroll
  for (int j = 0; j < 8; j++) { p[j] = __expf(l[j] - mx); sum += p[j]; }
  // top-2 (strict > keeps lowest index on ties, matching jax.lax.top_k)
  int i1 = 0;
#pragma unroll
  for (int j = 1; j < 8; j++) if (l[j] > l[i1]) i1 = j;
  int i2 = (i1 == 0) ? 1 : 0;
#pragma unroll
  for (int j = 0; j < 8; j++) if (j != i1 && l[j] > l[i2]) i2 = j;
  float p1 = p[i1] / sum, p2 = p[i2] / sum;
  float inv = 1.0f / (p1 + p2);
  if ((tid & 7) == 0) {
    topk_i[2 * tok] = i1; topk_i[2 * tok + 1] = i2;
    topk_w[2 * tok] = p1 * inv; topk_w[2 * tok + 1] = p2 * inv;
    atomicAdd(&counts[i1], 1);
    atomicAdd(&counts[i2], 1);
  }
}

// ---------------- prefix sum over 8 counts + zero cursors ----------------
__global__ void prefix_kernel(const int* __restrict__ counts, int* __restrict__ offsets,
                              int* __restrict__ cursors) {
  int t = threadIdx.x;
  if (t < NE) cursors[t] = 0;
  if (t == 0) {
    int run = 0;
    for (int e = 0; e < NE; e++) { offsets[e] = run; run += counts[e]; }
  }
}

// ---------------- scatter tokens into per-expert segments ----------------
__global__ __launch_bounds__(256) void scatter_kernel(const int* __restrict__ topk_i,
                                                      const float* __restrict__ topk_w,
                                                      const int* __restrict__ offsets,
                                                      int* __restrict__ cursors,
                                                      int* __restrict__ tok_list,
                                                      float* __restrict__ wt_list) {
  int t = blockIdx.x * 256 + threadIdx.x;
  if (t >= T_TOK) return;
#pragma unroll
  for (int k = 0; k < 2; k++) {
    int e = topk_i[2 * t + k];
    int pos = atomicAdd(&cursors[e], 1);
    int slot = offsets[e] + pos;
    tok_list[slot] = t;
    wt_list[slot] = topk_w[2 * t + k];
  }
}

// ---------------- GEMM1: h[slot] = gelu(x[tok] @ w1[e])  (M=cnt, N=4096, K=1024) ----------------
__global__ __launch_bounds__(256) void gemm1_kernel(
    const __hip_bfloat16* __restrict__ xb, const __hip_bfloat16* __restrict__ w1bt,
    const int* __restrict__ tok_list, const int* __restrict__ counts,
    const int* __restrict__ offsets, __hip_bfloat16* __restrict__ h) {
  const int e = blockIdx.y >> 7;
  const int mb = blockIdx.y & 127;
  const int cnt = counts[e];
  const int m0 = mb * 128;
  if (m0 >= cnt) return;
  const int rem = cnt - m0;
  const int seg = offsets[e];
  const int nb = blockIdx.x;  // 0..31

  __shared__ __align__(16) __hip_bfloat16 As[128 * 32];
  __shared__ __align__(16) __hip_bfloat16 Bs[128 * 32];

  const int tid = threadIdx.x;
  const __hip_bfloat16* wB = w1bt + ((size_t)e * DF + (size_t)nb * 128) * DM;

  // staging addresses (loop-invariant): idx covers 512 chunks of 16B per tile
  const __hip_bfloat16* gA[2]; const __hip_bfloat16* gB[2];
  char* lA[2]; char* lB[2];
#pragma unroll
  for (int i = 0; i < 2; i++) {
    int idx = tid + i * 256;
    int row = idx >> 2;
    int gg = (idx & 3) ^ ((row >> 1) & 3);  // XOR swizzle keeps LDS dest lane-contiguous
    int r = row < rem ? row : rem - 1;
    int tok = tok_list[seg + m0 + r];
    gA[i] = xb + (size_t)tok * DM + gg * 8;
    gB[i] = wB + (size_t)row * DM + gg * 8;
    lA[i] = (char*)As + idx * 16;
    lB[i] = (char*)Bs + idx * 16;
  }

  const int lane = tid & 63;
  const int wv = tid >> 6;
  const int wm = (wv >> 1) * 64, wn = (wv & 1) * 64;
  const int m16 = lane & 15, q = lane >> 4;

  const char* pa[4]; const char* pb[4];
#pragma unroll
  for (int mt = 0; mt < 4; mt++) {
    int row = wm + mt * 16 + m16;
    pa[mt] = (const char*)As + row * 64 + ((q ^ ((row >> 1) & 3)) * 16);
  }
#pragma unroll
  for (int nt = 0; nt < 4; nt++) {
    int row = wn + nt * 16 + m16;
    pb[nt] = (const char*)Bs + row * 64 + ((q ^ ((row >> 1) & 3)) * 16);
  }

  f32x4 acc[4][4] = {};

  for (int k0 = 0; k0 < DM; k0 += 32) {
    __syncthreads();
#pragma unroll
    for (int i = 0; i < 2; i++) {
      gload_lds16(gA[i] + k0, lA[i]);
      gload_lds16(gB[i] + k0, lB[i]);
    }
    __syncthreads();
    short8 av[4], bv[4];
#pragma unroll
    for (int mt = 0; mt < 4; mt++) av[mt] = *(const short8*)pa[mt];
#pragma unroll
    for (int nt = 0; nt < 4; nt++) bv[nt] = *(const short8*)pb[nt];
#pragma unroll
    for (int mt = 0; mt < 4; mt++)
#pragma unroll
      for (int nt = 0; nt < 4; nt++)
        acc[mt][nt] = __builtin_amdgcn_mfma_f32_16x16x32_bf16(av[mt], bv[nt], acc[mt][nt], 0, 0, 0);
  }

  // epilogue: exact gelu -> bf16
#pragma unroll
  for (int mt = 0; mt < 4; mt++) {
#pragma unroll
    for (int r = 0; r < 4; r++) {
      const int row = wm + mt * 16 + q * 4 + r;
      if (row < rem) {
        __hip_bfloat16* hr = h + (size_t)(seg + m0 + row) * DF + nb * 128 + wn + m16;
#pragma unroll
        for (int nt = 0; nt < 4; nt++) {
          float v = acc[mt][nt][r];
          v = 0.5f * v * (1.0f + erff(v * 0.70710678118654752f));
          hr[nt * 16] = __float2bfloat16(v);
        }
      }
    }
  }
}

// ---------------- GEMM2: out[tok] += wt * (h[slot] @ w2[e])  (M=cnt, N=1024, K=4096) ----------------
__global__ __launch_bounds__(256) void gemm2_kernel(
    const __hip_bfloat16* __restrict__ h, const __hip_bfloat16* __restrict__ w2bt,
    const int* __restrict__ tok_list, const float* __restrict__ wt_list,
    const int* __restrict__ counts, const int* __restrict__ offsets,
    float* __restrict__ out) {
  const int e = blockIdx.y >> 7;
  const int mb = blockIdx.y & 127;
  const int cnt = counts[e];
  const int m0 = mb * 128;
  if (m0 >= cnt) return;
  const int rem = cnt - m0;
  const int seg = offsets[e];
  const int nb = blockIdx.x;  // 0..7

  __shared__ __align__(16) __hip_bfloat16 As[128 * 32];
  __shared__ __align__(16) __hip_bfloat16 Bs[128 * 32];

  const int tid = threadIdx.x;
  const __hip_bfloat16* wB = w2bt + ((size_t)e * DM + (size_t)nb * 128) * DF;

  const __hip_bfloat16* gA[2]; const __hip_bfloat16* gB[2];
  char* lA[2]; char* lB[2];
#pragma unroll
  for (int i = 0; i < 2; i++) {
    int idx = tid + i * 256;
    int row = idx >> 2;
    int gg = (idx & 3) ^ ((row >> 1) & 3);
    int r = row < rem ? row : rem - 1;
    gA[i] = h + (size_t)(seg + m0 + r) * DF + gg * 8;
    gB[i] = wB + (size_t)row * DF + gg * 8;
    lA[i] = (char*)As + idx * 16;
    lB[i] = (char*)Bs + idx * 16;
  }

  const int lane = tid & 63;
  const int wv = tid >> 6;
  const int wm = (wv >> 1) * 64, wn = (wv & 1) * 64;
  const int m16 = lane & 15, q = lane >> 4;

  const char* pa[4]; const char* pb[4];
#pragma unroll
  for (int mt = 0; mt < 4; mt++) {
    int row = wm + mt * 16 + m16;
    pa[mt] = (const char*)As + row * 64 + ((q ^ ((row >> 1) & 3)) * 16);
  }
#pragma unroll
  for (int nt = 0; nt < 4; nt++) {
    int row = wn + nt * 16 + m16;
    pb[nt] = (const char*)Bs + row * 64 + ((q ^ ((row >> 1) & 3)) * 16);
  }

  f32x4 acc[4][4] = {};

  for (int k0 = 0; k0 < DF; k0 += 32) {
    __syncthreads();
#pragma unroll
    for (int i = 0; i < 2; i++) {
      gload_lds16(gA[i] + k0, lA[i]);
      gload_lds16(gB[i] + k0, lB[i]);
    }
    __syncthreads();
    short8 av[4], bv[4];
#pragma unroll
    for (int mt = 0; mt < 4; mt++) av[mt] = *(const short8*)pa[mt];
#pragma unroll
    for (int nt = 0; nt < 4; nt++) bv[nt] = *(const short8*)pb[nt];
#pragma unroll
    for (int mt = 0; mt < 4; mt++)
#pragma unroll
      for (int nt = 0; nt < 4; nt++)
        acc[mt][nt] = __builtin_amdgcn_mfma_f32_16x16x32_bf16(av[mt], bv[nt], acc[mt][nt], 0, 0, 0);
  }

  // epilogue: gate-weighted atomic accumulate into out
#pragma unroll
  for (int mt = 0; mt < 4; mt++) {
#pragma unroll
    for (int r = 0; r < 4; r++) {
      const int row = wm + mt * 16 + q * 4 + r;
      if (row < rem) {
        const int slot = seg + m0 + row;
        const int tok = tok_list[slot];
        const float wt = wt_list[slot];
        float* orow = out + (size_t)tok * DM + nb * 128 + wn + m16;
#pragma unroll
        for (int nt = 0; nt < 4; nt++)
          atomicAdd(&orow[nt * 16], wt * acc[mt][nt][r]);
      }
    }
  }
}

extern "C" void kernel_launch(void* const* d_in, const int* in_sizes, int n_in,
                              void* d_out, int out_size, void* d_ws, size_t ws_size,
                              hipStream_t stream) {
  const float* x = (const float*)d_in[0];
  const float* wr = (const float*)d_in[1];
  const float* w1 = (const float*)d_in[2];
  const float* w2 = (const float*)d_in[3];
  float* out = (float*)d_out;

  char* p = (char*)d_ws;
  __hip_bfloat16* xb = (__hip_bfloat16*)p;   p += (size_t)T_TOK * DM * 2;       // 32 MB
  __hip_bfloat16* w1bt = (__hip_bfloat16*)p; p += (size_t)NE * DM * DF * 2;     // 64 MB
  __hip_bfloat16* w2bt = (__hip_bfloat16*)p; p += (size_t)NE * DF * DM * 2;     // 64 MB
  __hip_bfloat16* h = (__hip_bfloat16*)p;    p += (size_t)2 * T_TOK * DF * 2;   // 256 MB
  int* tok_list = (int*)p;   p += (size_t)2 * T_TOK * 4;
  float* wt_list = (float*)p; p += (size_t)2 * T_TOK * 4;
  int* topk_i = (int*)p;     p += (size_t)T_TOK * 2 * 4;
  float* topk_w = (float*)p; p += (size_t)T_TOK * 2 * 4;
  int* counts = (int*)p;     p += 32;
  int* offsets = (int*)p;    p += 32;
  int* cursors = (int*)p;    p += 32;

  hipMemsetAsync(counts, 0, 32, stream);
  hipMemsetAsync(out, 0, (size_t)T_TOK * DM * 4, stream);

  cvt_x_kernel<<<T_TOK * DM / 8 / 256, 256, 0, stream>>>(x, xb);
  tcvt_kernel<<<dim3(DF / 32, DM / 32, NE), 256, 0, stream>>>(w1, w1bt, DM, DF);
  tcvt_kernel<<<dim3(DM / 32, DF / 32, NE), 256, 0, stream>>>(w2, w2bt, DF, DM);
  router_kernel<<<T_TOK / 32, 256, 0, stream>>>(x, wr, counts, topk_i, topk_w);
  prefix_kernel<<<1, 64, 0, stream>>>(counts, offsets, cursors);
  scatter_kernel<<<T_TOK / 256, 256, 0, stream>>>(topk_i, topk_w, offsets, cursors,
                                                  tok_list, wt_list);
  gemm1_kernel<<<dim3(DF / 128, NE * 128), 256, 0, stream>>>(xb, w1bt, tok_list, counts,
                                                             offsets, h);
  gemm2_kernel<<<dim3(DM / 128, NE * 128), 256, 0, stream>>>(h, w2bt, tok_list, wt_list,
                                                             counts, offsets, out);
}